// Round 5
// baseline (822.332 us; speedup 1.0000x reference)
//
#include <hip/hip_runtime.h>

#define NCAM 6
#define FC   128
#define FH_  32
#define FW_  88
#define NPIX (FH_*FW_)        // 2816
#define PH   34
#define PW   90
#define PPIX (PH*PW)          // 3060 padded plane
#define ND   41
#define X3D  42               // 41 depth + 1 opacity planes
#define OUTC 128
#define GTOT (NCAM*NPIX)      // 16896
#define BEVH 100
#define BEVW 100
#define NPXB (BEVH*BEVW)      // 10000
#define NTILE 25              // 25x25 tiles of 4x4 px
#define NWORD 264             // 16896/64 mask words per tile
#define NSEG  8               // segments per tile (parallel compositing)
#define SEGW  33              // words per segment
#define NCHUNK 9              // ceil(33/4) 4-word chunks per segment

// ---- ws layout (float offsets). Total 5.55M floats = 22.2 MB ----
#define WS_CAM    0                          // 144 floats
#define WS_X1P    256                        // padded conv1 out: 6*128*3060 = 2350080
#define WS_X2P    (WS_X1P + NCAM*FC*PPIX)    // padded conv2 out: 2350080
#define WS_X3D    (WS_X2P + NCAM*FC*PPIX)    // 6*42*2816 = 709632
#define WS_GAUSS  (WS_X3D + NCAM*X3D*NPIX)   // 16896*8 = 135168
#define WS_COLORS WS_X1P                     // X1P dead after conv2 (2162688 <= 2350080)
#define WS_MASKS  WS_X2P                     // X2P dead after conv1x1 (330000 floats)
#define WS_B      (WS_X2P + 330000)          // [625][16][8] = 80000 floats

__device__ inline void inv3x3(const float* m, float* o) {
    float a=m[0],b=m[1],c=m[2],d=m[3],e=m[4],f=m[5],g=m[6],h=m[7],i=m[8];
    float A=e*i-f*h, B=c*h-b*i, C=b*f-c*e;
    float Dd=f*g-d*i, E=a*i-c*g, F=c*d-a*f;
    float Gg=d*h-e*g, H=b*g-a*h, I=a*e-b*d;
    float r = 1.0f/(a*A + b*Dd + c*Gg);
    o[0]=A*r; o[1]=B*r; o[2]=C*r; o[3]=Dd*r; o[4]=E*r; o[5]=F*r;
    o[6]=Gg*r; o[7]=H*r; o[8]=I*r;
}

__global__ void cam_consts_kernel(const float* __restrict__ rot, const float* __restrict__ tr,
                                  const float* __restrict__ intr, const float* __restrict__ prot,
                                  const float* __restrict__ ptr_, float* __restrict__ cam) {
    int n = threadIdx.x;
    if (n >= NCAM) return;
    float M1[9], Ki[9];
    inv3x3(prot + n*9, M1);
    inv3x3(intr + n*9, Ki);
    const float* R = rot + n*9;
    float* c = cam + n*24;
    for (int i=0;i<9;i++) c[i] = M1[i];
    for (int i=0;i<3;i++) c[9+i] = ptr_[n*3+i];
    for (int i=0;i<3;i++)
        for (int j=0;j<3;j++)
            c[12+i*3+j] = R[i*3+0]*Ki[0+j] + R[i*3+1]*Ki[3+j] + R[i*3+2]*Ki[6+j];
    for (int i=0;i<3;i++) c[21+i] = tr[n*3+i];
}

// 3x3 conv + folded BN + ReLU, 1 px/thread for full occupancy.
// PAD_IN: input is padded [34][90] planes (no bounds checks, 9 imm-offset loads).
// Output always padded (border pre-zeroed by memset).
template<bool PAD_IN>
__global__ __launch_bounds__(256) void conv3x3_kernel(
        const float* __restrict__ in, float* __restrict__ out, const float* __restrict__ w,
        const float* __restrict__ cb, const float* __restrict__ bg, const float* __restrict__ bb,
        const float* __restrict__ bm, const float* __restrict__ bv) {
    const int n   = blockIdx.x;
    const int co0 = blockIdx.y * 4;
    const int t   = threadIdx.x;
    const int px  = blockIdx.z * 256 + t;       // 11*256 = 2816 exact
    const int y   = px / FW_, x = px - y*FW_;
    float scale[4], shift[4];
    #pragma unroll
    for (int c=0;c<4;c++) {
        float s = bg[co0+c] * rsqrtf(bv[co0+c] + 1e-3f);
        scale[c] = s;
        shift[c] = (cb[co0+c] - bm[co0+c]) * s + bb[co0+c];
    }
    float acc[4] = {0.f,0.f,0.f,0.f};
    const float* wb = w + (size_t)co0*FC*9;
    if (PAD_IN) {
        const float* ip = in + (size_t)n*FC*PPIX + y*PW + x;   // window top-left in padded coords
        for (int ci=0; ci<FC; ++ci) {
            float v[9];
            #pragma unroll
            for (int dy=0;dy<3;dy++)
                #pragma unroll
                for (int dx=0;dx<3;dx++) v[dy*3+dx] = ip[dy*PW + dx];
            #pragma unroll
            for (int c=0;c<4;c++) {
                const float* wr = wb + (size_t)c*FC*9 + ci*9;
                float a = acc[c];
                a = fmaf(wr[0], v[0], a); a = fmaf(wr[1], v[1], a); a = fmaf(wr[2], v[2], a);
                a = fmaf(wr[3], v[3], a); a = fmaf(wr[4], v[4], a); a = fmaf(wr[5], v[5], a);
                a = fmaf(wr[6], v[6], a); a = fmaf(wr[7], v[7], a); a = fmaf(wr[8], v[8], a);
                acc[c] = a;
            }
            ip += PPIX;
        }
    } else {
        const float* ib = in + (size_t)n*FC*NPIX;
        for (int ci=0; ci<FC; ++ci) {
            const float* ip = ib + (size_t)ci*NPIX;
            float v[9];
            #pragma unroll
            for (int dy=0;dy<3;dy++) {
                int yy = y + dy - 1;
                bool yok = (unsigned)yy < (unsigned)FH_;
                #pragma unroll
                for (int dx=0;dx<3;dx++) {
                    int xx = x + dx - 1;
                    v[dy*3+dx] = (yok && (unsigned)xx < (unsigned)FW_) ? ip[yy*FW_ + xx] : 0.0f;
                }
            }
            #pragma unroll
            for (int c=0;c<4;c++) {
                const float* wr = wb + (size_t)c*FC*9 + ci*9;
                float a = acc[c];
                a = fmaf(wr[0], v[0], a); a = fmaf(wr[1], v[1], a); a = fmaf(wr[2], v[2], a);
                a = fmaf(wr[3], v[3], a); a = fmaf(wr[4], v[4], a); a = fmaf(wr[5], v[5], a);
                a = fmaf(wr[6], v[6], a); a = fmaf(wr[7], v[7], a); a = fmaf(wr[8], v[8], a);
                acc[c] = a;
            }
        }
    }
    const int po = (y+1)*PW + (x+1);
    #pragma unroll
    for (int c=0;c<4;c++)
        out[((size_t)n*FC + co0 + c)*PPIX + po] = fmaxf(fmaf(acc[c], scale[c], shift[c]), 0.0f);
}

// 1x1 conv reading padded X2; depth+opacity (co<42) -> X3D planes,
// feature channels (co>=42) -> colors[g][128] directly (aligned float4 scatter).
__global__ __launch_bounds__(256) void conv1x1_kernel(const float* __restrict__ in,
        float* __restrict__ x3d, float* __restrict__ colors,
        const float* __restrict__ w, const float* __restrict__ b) {
    const int n  = blockIdx.x;
    const int g  = blockIdx.y;                   // 0..42
    const int t  = threadIdx.x;
    const int px = blockIdx.z * 256 + t;
    const int y  = px / FW_, x = px - y*FW_;
    const int pp = (y+1)*PW + (x+1);
    const bool iscolor = (g >= 11);
    const int co0 = iscolor ? (42 + 4*(g-11)) : g*4;
    const int nc  = (g == 10) ? 2 : 4;
    float acc[4];
    #pragma unroll
    for (int c=0;c<4;c++) acc[c] = (c < nc) ? b[co0+c] : 0.0f;
    const float* ip = in + (size_t)n*FC*PPIX + pp;
    for (int ci=0; ci<FC; ++ci) {
        float v = ip[(size_t)ci*PPIX];
        #pragma unroll
        for (int c=0;c<4;c++)
            if (c < nc) acc[c] = fmaf(w[(size_t)(co0+c)*FC + ci], v, acc[c]);
    }
    if (iscolor) {
        *(float4*)(colors + (((size_t)(n*NPIX + px)) << 7) + (co0 - 42)) =
            make_float4(acc[0], acc[1], acc[2], acc[3]);
    } else {
        #pragma unroll
        for (int c=0;c<4;c++)
            if (c < nc) x3d[((size_t)n*X3D + co0 + c)*NPIX + px] = acc[c];
    }
}

// per-gaussian: softmax over depth, xy moments, splat params {my,mx,A,B,C,qm,ri,rj}
__global__ __launch_bounds__(256) void moments_kernel(const float* __restrict__ x3,
        const float* __restrict__ cam, float* __restrict__ gauss, float* __restrict__ ng) {
    int gi = blockIdx.x*256 + threadIdx.x;
    int n  = gi / NPIX;
    int p  = gi - n*NPIX;
    int h  = p / FW_, xp = p - h*FW_;
    const float* cc = cam + n*24;
    float u = xp * (703.0f/87.0f);
    float v = h  * (255.0f/31.0f);
    float fx = u - cc[9], fy = v - cc[10], fz = -cc[11];
    float p0x = cc[0]*fx + cc[1]*fy + cc[2]*fz;
    float p0y = cc[3]*fx + cc[4]*fy + cc[5]*fz;
    float p0z = cc[6]*fx + cc[7]*fy + cc[8]*fz;
    const float* lg = x3 + (size_t)n*X3D*NPIX + p;

    float mxl = -1e30f;
    for (int d=0; d<ND; ++d) mxl = fmaxf(mxl, lg[(size_t)d*NPIX]);
    float s=0.f, sgx=0.f, sgy=0.f;
    for (int d=0; d<ND; ++d) {
        float e  = __expf(lg[(size_t)d*NPIX] - mxl);
        float dz = 4.0f + (float)d;
        float pz = p0z + dz*cc[8];
        float px = (p0x + dz*cc[2]) * pz;
        float py = (p0y + dz*cc[5]) * pz;
        float gx = cc[12]*px + cc[13]*py + cc[14]*pz + cc[21];
        float gy = cc[15]*px + cc[16]*py + cc[17]*pz + cc[22];
        s += e; sgx += e*gx; sgy += e*gy;
    }
    float inv_s = 1.0f/s;
    float mex = sgx*inv_s, mey = sgy*inv_s;
    float cxx=0.f, cxy=0.f, cyy=0.f;
    for (int d=0; d<ND; ++d) {
        float e  = __expf(lg[(size_t)d*NPIX] - mxl);
        float dz = 4.0f + (float)d;
        float pz = p0z + dz*cc[8];
        float px = (p0x + dz*cc[2]) * pz;
        float py = (p0y + dz*cc[5]) * pz;
        float gx = cc[12]*px + cc[13]*py + cc[14]*pz + cc[21];
        float gy = cc[15]*px + cc[16]*py + cc[17]*pz + cc[22];
        float dxv = gx - mex, dyv = gy - mey;
        cxx += e*dxv*dxv; cxy += e*dxv*dyv; cyy += e*dyv*dyv;
    }
    const float k9 = inv_s * (1.0f/9.0f);
    cxx *= k9; cxy *= k9; cyy *= k9;

    float lo = lg[(size_t)ND*NPIX];
    float op = 1.0f/(1.0f + __expf(-lo));
    bool mask = op > 0.05f;

    const float SC = 0.02f, SH = 50.0f, SW = 50.0f;
    float my = -SH*(mey*SC) + 50.0f;
    float mx = -SW*(mex*SC) + 50.0f;
    float a  = SH*SH*(cyy*SC*SC) + 0.3f;
    float b  = SH*SW*(cxy*SC*SC);
    float c  = SW*SW*(cxx*SC*SC) + 0.3f;
    float det = a*c - b*b;
    bool valid = mask && (det > 0.0f);
    float A, Bc, C, qm, ri, rj;
    if (valid) {
        float idet = 1.0f/det;
        A = c*idet; Bc = -b*idet; C = a*idet;
        qm = 2.0f*__logf(255.0f*op);
        ri = sqrtf(qm*a); rj = sqrtf(qm*c);
    } else { A=Bc=C=0.f; qm=-1.0f; ri=-1e30f; rj=-1e30f; }
    float* gp = gauss + (size_t)gi*8;
    gp[0]=my; gp[1]=mx; gp[2]=A; gp[3]=Bc; gp[4]=C; gp[5]=qm; gp[6]=ri; gp[7]=rj;

    unsigned long long bal = __ballot(mask);
    if ((threadIdx.x & 63) == 0) atomicAdd(ng, (float)__popcll(bal));
}

// bin gaussians into per-tile 64-g-word bitmasks
__global__ __launch_bounds__(256) void build_masks_kernel(const float* __restrict__ gauss,
        unsigned long long* __restrict__ masks) {
    const int g = blockIdx.x*256 + threadIdx.x;
    const float4 g0 = *(const float4*)(gauss + ((size_t)g << 3));
    const float4 g1 = *(const float4*)(gauss + ((size_t)g << 3) + 4);
    if (g1.y < 0.0f) return;
    const float my = g0.x, mx = g0.y, ri = g1.z, rj = g1.w;
    int ti0 = (int)floorf((my - ri) * 0.25f);
    int ti1 = (int)floorf((my + ri) * 0.25f);
    int tj0 = (int)floorf((mx - rj) * 0.25f);
    int tj1 = (int)floorf((mx + rj) * 0.25f);
    ti0 = max(ti0, 0); tj0 = max(tj0, 0);
    ti1 = min(ti1, NTILE-1); tj1 = min(tj1, NTILE-1);
    const int wi = g >> 6;
    const unsigned long long bit = 1ull << (g & 63);
    for (int ti = ti0; ti <= ti1; ++ti)
        for (int tj = tj0; tj <= tj1; ++tj)
            atomicOr(&masks[(size_t)(ti*NTILE + tj)*NWORD + wi], bit);
}

__device__ inline float eval_alpha(const float4 g0, const float4 g1, float fi, float fj) {
    float dI = fi - g0.x, dJ = fj - g0.y;
    float q = dI*(g0.z*dI + 2.0f*g0.w*dJ) + g1.x*dJ*dJ;
    if (q < 0.0f || q > g1.y) return 0.0f;
    return fminf(0.99f, 0.003921568627f * __expf(0.5f*(g1.y - q)));
}

// per (tile, segment): S[tile][px][seg] = sum of log(1-alpha) over segment hits.
__global__ __launch_bounds__(256) void seg_sums_kernel(const float* __restrict__ gauss,
        const unsigned long long* __restrict__ masks, float* __restrict__ B) {
    __shared__ unsigned long long s_words[SEGW];
    __shared__ float sp[256][17];
    __shared__ float sp2[16][17];
    const int tile = blockIdx.x, seg = blockIdx.y;
    const int t = threadIdx.x;
    const int i0 = (tile / NTILE) * 4, j0 = (tile % NTILE) * 4;
    if (t < SEGW) s_words[t] = masks[(size_t)tile*NWORD + seg*SEGW + t];
    __syncthreads();
    float ls[16];
    #pragma unroll
    for (int p=0;p<16;p++) ls[p] = 0.0f;
    for (int idx = t; idx < SEGW*64; idx += 256) {
        int wd = idx >> 6, ln = idx & 63;
        if ((s_words[wd] >> ln) & 1ull) {
            int g = ((seg*SEGW + wd) << 6) + ln;
            float4 g0 = *(const float4*)(gauss + ((size_t)g << 3));
            float4 g1 = *(const float4*)(gauss + ((size_t)g << 3) + 4);
            #pragma unroll
            for (int p=0;p<16;p++) {
                float al = eval_alpha(g0, g1, (float)(i0 + (p>>2)), (float)(j0 + (p&3)));
                if (al > 0.0f) ls[p] += __logf(1.0f - al);
            }
        }
    }
    #pragma unroll
    for (int p=0;p<16;p++) sp[t][p] = ls[p];
    __syncthreads();
    const int px = t & 15, grp = t >> 4;
    float s2 = 0.0f;
    #pragma unroll
    for (int r=0;r<16;r++) s2 += sp[grp*16 + r][px];
    sp2[grp][px] = s2;
    __syncthreads();
    if (t < 16) {
        float s3 = 0.0f;
        #pragma unroll
        for (int g2=0;g2<16;g2++) s3 += sp2[g2][t];
        B[(size_t)(tile*16 + t)*NSEG + seg] = s3;
    }
}

// per (tile, segment): weights via parallel log-space prefix scan (matches the
// reference's log1p/cumsum/exp formulation), then dependency-free weighted sum.
__global__ __launch_bounds__(256) void seg_composite_kernel(const float* __restrict__ gauss,
        const float* __restrict__ colors, const unsigned long long* __restrict__ masks,
        const float* __restrict__ B, float* __restrict__ out) {
    __shared__ unsigned long long s_words[36];
    __shared__ float s_w[256][17];       // [slot][px] weights (pad 17: conflict-free)
    __shared__ float s_wsum[4][17];      // per-wave inclusive totals per px
    __shared__ float s_base[16];         // running log-T per px
    __shared__ unsigned long long s_hitm[4];
    __shared__ unsigned int s_ne;
    const int tile = blockIdx.x, seg = blockIdx.y;
    const int t = threadIdx.x;
    const int wave = t >> 6, lane = t & 63;
    const int i0 = (tile / NTILE) * 4, j0 = (tile % NTILE) * 4;

    if (t < SEGW) s_words[t] = masks[(size_t)tile*NWORD + seg*SEGW + t];
    if (t >= SEGW && t < 36) s_words[t] = 0ull;
    if (t < 16) {
        float b = 0.0f;
        for (int s = 0; s < seg; ++s) b += B[(size_t)(tile*16 + t)*NSEG + s];
        s_base[t] = b;
    }
    __syncthreads();
    if (wave == 0) {
        bool ne = (lane < NCHUNK) &&
                  ((s_words[lane*4] | s_words[lane*4+1] | s_words[lane*4+2] | s_words[lane*4+3]) != 0ull);
        unsigned long long bal = __ballot(ne);
        if (lane == 0) s_ne = (unsigned int)bal;
    }
    __syncthreads();
    unsigned int nem = s_ne;
    if (nem == 0u) return;

    const int px = t >> 4, cs = t & 15;
    float4 acc0 = make_float4(0.f,0.f,0.f,0.f);
    float4 acc1 = make_float4(0.f,0.f,0.f,0.f);

    while (nem) {
        int c = __builtin_ctz(nem); nem &= nem - 1;
        const int wrel = (c << 2) + wave;
        unsigned long long m = s_words[wrel];
        bool active = (m >> lane) & 1ull;
        float a16[16];
        bool anyhit = false;
        float4 g0, g1;
        if (active) {
            int g = ((seg*SEGW + wrel) << 6) + lane;
            g0 = *(const float4*)(gauss + ((size_t)g << 3));
            g1 = *(const float4*)(gauss + ((size_t)g << 3) + 4);
        }
        #pragma unroll
        for (int p=0;p<16;p++) {
            float a = active ? eval_alpha(g0, g1, (float)(i0 + (p>>2)), (float)(j0 + (p&3))) : 0.0f;
            a16[p] = a;
            anyhit |= (a > 0.0f);
            float lv = (a > 0.0f) ? __logf(1.0f - a) : 0.0f;
            // wave-level inclusive scan of lv over lanes
            float v = lv;
            #pragma unroll
            for (int off=1; off<64; off<<=1) {
                float uu = __shfl_up(v, (unsigned)off, 64);
                if (lane >= off) v += uu;
            }
            if (lane == 63) s_wsum[wave][p] = v;
            s_w[t][p] = v - lv;              // exclusive-within-wave prefix (temp)
        }
        unsigned long long hb = __ballot(anyhit);
        if (lane == 0) s_hitm[wave] = hb;
        __syncthreads();                      // s_wsum, s_hitm, temp prefixes ready
        #pragma unroll
        for (int p=0;p<16;p++) {
            float cross = 0.0f;
            #pragma unroll
            for (int w2=0; w2<4; ++w2) if (w2 < wave) cross += s_wsum[w2][p];
            float wv = (a16[p] > 0.0f)
                     ? a16[p] * __expf(s_base[p] + cross + s_w[t][p]) : 0.0f;
            s_w[t][p] = wv;
        }
        __syncthreads();                      // s_w = final weights
        if (t < 16)
            s_base[t] += s_wsum[0][t] + s_wsum[1][t] + s_wsum[2][t] + s_wsum[3][t];
        // ---- dependency-free weighted accumulation over union hits ----
        #pragma unroll
        for (int w2 = 0; w2 < 4; ++w2) {
            unsigned long long hm = s_hitm[w2];
            const int gbase = ((seg*SEGW + (c << 2) + w2) << 6);
            while (hm) {
                int b = __builtin_ctzll(hm); hm &= hm - 1;
                float wv = s_w[(w2 << 6) + b][px];
                if (wv > 0.0f) {
                    const float* cp = colors + (((size_t)(gbase + b)) << 7) + (cs << 3);
                    float4 c0 = *(const float4*)cp;
                    float4 c1 = *(const float4*)(cp + 4);
                    acc0.x = fmaf(wv, c0.x, acc0.x); acc0.y = fmaf(wv, c0.y, acc0.y);
                    acc0.z = fmaf(wv, c0.z, acc0.z); acc0.w = fmaf(wv, c0.w, acc0.w);
                    acc1.x = fmaf(wv, c1.x, acc1.x); acc1.y = fmaf(wv, c1.y, acc1.y);
                    acc1.z = fmaf(wv, c1.z, acc1.z); acc1.w = fmaf(wv, c1.w, acc1.w);
                }
            }
        }
        __syncthreads();                      // protect s_w/s_base before next chunk
    }

    const int pixg = (i0 + (px >> 2)) * BEVW + (j0 + (px & 3));
    float* op = out + (size_t)(cs << 3) * NPXB + pixg;
    atomicAdd(op + 0*NPXB, acc0.x); atomicAdd(op + 1*NPXB, acc0.y);
    atomicAdd(op + 2*NPXB, acc0.z); atomicAdd(op + 3*NPXB, acc0.w);
    atomicAdd(op + 4*NPXB, acc1.x); atomicAdd(op + 5*NPXB, acc1.y);
    atomicAdd(op + 6*NPXB, acc1.z); atomicAdd(op + 7*NPXB, acc1.w);
}

extern "C" void kernel_launch(void* const* d_in, const int* in_sizes, int n_in,
                              void* d_out, int out_size, void* d_ws, size_t ws_size,
                              hipStream_t stream) {
    const float* rot  = (const float*)d_in[0];
    const float* tr   = (const float*)d_in[1];
    const float* intr = (const float*)d_in[2];
    const float* prot = (const float*)d_in[3];
    const float* ptr_ = (const float*)d_in[4];
    const float* img  = (const float*)d_in[5];
    const float* c1w  = (const float*)d_in[6];  const float* c1b = (const float*)d_in[7];
    const float* b1g  = (const float*)d_in[8];  const float* b1b = (const float*)d_in[9];
    const float* b1m  = (const float*)d_in[10]; const float* b1v = (const float*)d_in[11];
    const float* c2w  = (const float*)d_in[12]; const float* c2b = (const float*)d_in[13];
    const float* b2g  = (const float*)d_in[14]; const float* b2b = (const float*)d_in[15];
    const float* b2m  = (const float*)d_in[16]; const float* b2v = (const float*)d_in[17];
    const float* c3w  = (const float*)d_in[18]; const float* c3b = (const float*)d_in[19];
    float* out = (float*)d_out;
    float* ws  = (float*)d_ws;
    float* CAM = ws + WS_CAM;
    float* X1P = ws + WS_X1P;
    float* X2P = ws + WS_X2P;
    float* X3B = ws + WS_X3D;                 // depth+opacity planes (renamed: X3D is a macro)
    float* GS  = ws + WS_GAUSS;
    float* COL = ws + WS_COLORS;
    unsigned long long* MASKS = (unsigned long long*)(ws + WS_MASKS);
    float* Bsums = ws + WS_B;
    float* ngp = out + (size_t)NPXB*OUTC;

    cam_consts_kernel<<<1, 64, 0, stream>>>(rot, tr, intr, prot, ptr_, CAM);
    // zero padded activation buffers (borders must be 0 for the next conv)
    (void)hipMemsetAsync(X1P, 0, (size_t)NCAM*FC*PPIX*sizeof(float), stream);
    (void)hipMemsetAsync(X2P, 0, (size_t)NCAM*FC*PPIX*sizeof(float), stream);
    conv3x3_kernel<false><<<dim3(NCAM,32,11), 256, 0, stream>>>(img, X1P, c1w, c1b, b1g, b1b, b1m, b1v);
    conv3x3_kernel<true ><<<dim3(NCAM,32,11), 256, 0, stream>>>(X1P, X2P, c2w, c2b, b2g, b2b, b2m, b2v);
    conv1x1_kernel<<<dim3(NCAM,43,11), 256, 0, stream>>>(X2P, X3B, COL, c3w, c3b);
    // X2P dead now -> reuse for masks + segment sums
    (void)hipMemsetAsync(MASKS, 0, (size_t)NTILE*NTILE*NWORD*sizeof(unsigned long long), stream);
    (void)hipMemsetAsync(ngp, 0, sizeof(float), stream);
    (void)hipMemsetAsync(out, 0, (size_t)NPXB*OUTC*sizeof(float), stream);
    moments_kernel<<<GTOT/256, 256, 0, stream>>>(X3B, CAM, GS, ngp);
    build_masks_kernel<<<GTOT/256, 256, 0, stream>>>(GS, MASKS);
    seg_sums_kernel<<<dim3(NTILE*NTILE, NSEG), 256, 0, stream>>>(GS, MASKS, Bsums);
    seg_composite_kernel<<<dim3(NTILE*NTILE, NSEG), 256, 0, stream>>>(GS, COL, MASKS, Bsums, out);
}

// Round 6
// 791.443 us; speedup vs baseline: 1.0390x; 1.0390x over previous
//
#include <hip/hip_runtime.h>

#define NCAM 6
#define FC   128
#define FH_  32
#define FW_  88
#define NPIX (FH_*FW_)        // 2816
#define PH   34
#define PW   90
#define PPIX (PH*PW)          // 3060 padded plane
#define ND   41
#define X3D  42               // 41 depth + 1 opacity planes
#define OUTC 128
#define GTOT (NCAM*NPIX)      // 16896
#define BEVH 100
#define BEVW 100
#define NPXB (BEVH*BEVW)      // 10000
#define NTILE 25              // 25x25 tiles of 4x4 px
#define NWORDP 272            // padded mask words per tile (264 real, rest 0)
#define NSEG  16              // segments per tile
#define SEGW  17              // words per segment (16*17 = 272)

// ---- ws layout (float offsets). Total 5.55M floats = 22.2 MB ----
#define WS_CAM  0                        // 144 floats
#define WS_A    256                      // region A: IMGP -> X2P -> masks+Bsums (2350080)
#define WS_RB   (WS_A  + NCAM*FC*PPIX)   // region B: X1P -> colors (2350080)
#define WS_X3   (WS_RB + NCAM*FC*PPIX)   // depth+opacity planes 6*42*2816 = 709632
#define WS_GS   (WS_X3 + NCAM*X3D*NPIX)  // gauss params 16896*8 = 135168
#define A_BSUM  340000                   // Bsums offset inside region A (after 1.36MB masks)

__device__ inline void inv3x3(const float* m, float* o) {
    float a=m[0],b=m[1],c=m[2],d=m[3],e=m[4],f=m[5],g=m[6],h=m[7],i=m[8];
    float A=e*i-f*h, B=c*h-b*i, C=b*f-c*e;
    float Dd=f*g-d*i, E=a*i-c*g, F=c*d-a*f;
    float Gg=d*h-e*g, H=b*g-a*h, I=a*e-b*d;
    float r = 1.0f/(a*A + b*Dd + c*Gg);
    o[0]=A*r; o[1]=B*r; o[2]=C*r; o[3]=Dd*r; o[4]=E*r; o[5]=F*r;
    o[6]=Gg*r; o[7]=H*r; o[8]=I*r;
}

__global__ void cam_consts_kernel(const float* __restrict__ rot, const float* __restrict__ tr,
                                  const float* __restrict__ intr, const float* __restrict__ prot,
                                  const float* __restrict__ ptr_, float* __restrict__ cam) {
    int n = threadIdx.x;
    if (n >= NCAM) return;
    float M1[9], Ki[9];
    inv3x3(prot + n*9, M1);
    inv3x3(intr + n*9, Ki);
    const float* R = rot + n*9;
    float* c = cam + n*24;
    for (int i=0;i<9;i++) c[i] = M1[i];
    for (int i=0;i<3;i++) c[9+i] = ptr_[n*3+i];
    for (int i=0;i<3;i++)
        for (int j=0;j<3;j++)
            c[12+i*3+j] = R[i*3+0]*Ki[0+j] + R[i*3+1]*Ki[3+j] + R[i*3+2]*Ki[6+j];
    for (int i=0;i<3;i++) c[21+i] = tr[n*3+i];
}

// copy raw input [n][c][32][88] into padded [n][c][34][90] (border pre-zeroed)
__global__ __launch_bounds__(256) void pad_input_kernel(const float* __restrict__ src,
                                                        float* __restrict__ dst) {
    int idx = blockIdx.x*256 + threadIdx.x;        // 8448*256 == 2162688 exact
    int plane = idx / NPIX, px = idx - plane*NPIX;
    int y = px / FW_, x = px - y*FW_;
    dst[(size_t)plane*PPIX + (y+1)*PW + (x+1)] = src[idx];
}

// 3x3 conv + folded BN + ReLU. 4 px/thread (3x6 sliding window: 4.5 loads/px),
// padded input AND output. grid (NCAM, 32 co-groups, 3 quad-chunks).
__global__ __launch_bounds__(256) void conv3x3_q_kernel(
        const float* __restrict__ in, float* __restrict__ out, const float* __restrict__ w,
        const float* __restrict__ cb, const float* __restrict__ bg, const float* __restrict__ bb,
        const float* __restrict__ bm, const float* __restrict__ bv) {
    const int n   = blockIdx.x;
    const int co0 = blockIdx.y * 4;
    const int qid = blockIdx.z * 256 + threadIdx.x;   // 0..767, 704 valid
    if (qid >= 704) return;
    const int y = qid / 22, x0 = (qid - y*22) * 4;
    float scale[4], shift[4];
    #pragma unroll
    for (int c=0;c<4;c++) {
        float s = bg[co0+c] * rsqrtf(bv[co0+c] + 1e-3f);
        scale[c] = s;
        shift[c] = (cb[co0+c] - bm[co0+c]) * s + bb[co0+c];
    }
    float acc[4][4] = {};
    const float* ip = in + (size_t)n*FC*PPIX + y*PW + x0;  // window top-left (padded coords)
    const float* wb = w + (size_t)co0*FC*9;
    for (int ci=0; ci<FC; ++ci) {
        float v[3][6];
        #pragma unroll
        for (int r=0;r<3;r++)
            #pragma unroll
            for (int c6=0;c6<6;c6++) v[r][c6] = ip[r*PW + c6];
        #pragma unroll
        for (int c=0;c<4;c++) {
            const float* wr = wb + (size_t)c*FC*9 + ci*9;   // uniform -> s_load
            float w00=wr[0],w01=wr[1],w02=wr[2],w10=wr[3],w11=wr[4],
                  w12=wr[5],w20=wr[6],w21=wr[7],w22=wr[8];
            #pragma unroll
            for (int p=0;p<4;p++) {
                float a = acc[c][p];
                a = fmaf(w00, v[0][p], a); a = fmaf(w01, v[0][p+1], a); a = fmaf(w02, v[0][p+2], a);
                a = fmaf(w10, v[1][p], a); a = fmaf(w11, v[1][p+1], a); a = fmaf(w12, v[1][p+2], a);
                a = fmaf(w20, v[2][p], a); a = fmaf(w21, v[2][p+1], a); a = fmaf(w22, v[2][p+2], a);
                acc[c][p] = a;
            }
        }
        ip += PPIX;
    }
    #pragma unroll
    for (int c=0;c<4;c++) {
        float* op = out + ((size_t)n*FC + co0 + c)*PPIX + (y+1)*PW + (x0+1);
        #pragma unroll
        for (int p=0;p<4;p++)
            op[p] = fmaxf(fmaf(acc[c][p], scale[c], shift[c]), 0.0f);
    }
}

// 1x1 conv reading padded X2; depth+opacity (co<42) -> x3d planes,
// feature channels (co>=42) -> colors[g][128] directly (aligned float4).
__global__ __launch_bounds__(256) void conv1x1_kernel(const float* __restrict__ in,
        float* __restrict__ x3d, float* __restrict__ colors,
        const float* __restrict__ w, const float* __restrict__ b) {
    const int n  = blockIdx.x;
    const int g  = blockIdx.y;                   // 0..42
    const int t  = threadIdx.x;
    const int px = blockIdx.z * 256 + t;         // 11*256 = 2816 exact
    const int y  = px / FW_, x = px - y*FW_;
    const int pp = (y+1)*PW + (x+1);
    const bool iscolor = (g >= 11);
    const int co0 = iscolor ? (42 + 4*(g-11)) : g*4;
    const int nc  = (g == 10) ? 2 : 4;
    float acc[4];
    #pragma unroll
    for (int c=0;c<4;c++) acc[c] = (c < nc) ? b[co0+c] : 0.0f;
    const float* ip = in + (size_t)n*FC*PPIX + pp;
    for (int ci=0; ci<FC; ++ci) {
        float v = ip[(size_t)ci*PPIX];
        #pragma unroll
        for (int c=0;c<4;c++)
            if (c < nc) acc[c] = fmaf(w[(size_t)(co0+c)*FC + ci], v, acc[c]);
    }
    if (iscolor) {
        *(float4*)(colors + (((size_t)(n*NPIX + px)) << 7) + (co0 - 42)) =
            make_float4(acc[0], acc[1], acc[2], acc[3]);
    } else {
        #pragma unroll
        for (int c=0;c<4;c++)
            if (c < nc) x3d[((size_t)n*X3D + co0 + c)*NPIX + px] = acc[c];
    }
}

// per-gaussian: softmax over depth, xy moments, splat params {my,mx,A,B,C,qm,ri,rj}
__global__ __launch_bounds__(256) void moments_kernel(const float* __restrict__ x3,
        const float* __restrict__ cam, float* __restrict__ gauss, float* __restrict__ ng) {
    int gi = blockIdx.x*256 + threadIdx.x;
    int n  = gi / NPIX;
    int p  = gi - n*NPIX;
    int h  = p / FW_, xp = p - h*FW_;
    const float* cc = cam + n*24;
    float u = xp * (703.0f/87.0f);
    float v = h  * (255.0f/31.0f);
    float fx = u - cc[9], fy = v - cc[10], fz = -cc[11];
    float p0x = cc[0]*fx + cc[1]*fy + cc[2]*fz;
    float p0y = cc[3]*fx + cc[4]*fy + cc[5]*fz;
    float p0z = cc[6]*fx + cc[7]*fy + cc[8]*fz;
    const float* lg = x3 + (size_t)n*X3D*NPIX + p;

    float mxl = -1e30f;
    for (int d=0; d<ND; ++d) mxl = fmaxf(mxl, lg[(size_t)d*NPIX]);
    float s=0.f, sgx=0.f, sgy=0.f;
    for (int d=0; d<ND; ++d) {
        float e  = __expf(lg[(size_t)d*NPIX] - mxl);
        float dz = 4.0f + (float)d;
        float pz = p0z + dz*cc[8];
        float px = (p0x + dz*cc[2]) * pz;
        float py = (p0y + dz*cc[5]) * pz;
        float gx = cc[12]*px + cc[13]*py + cc[14]*pz + cc[21];
        float gy = cc[15]*px + cc[16]*py + cc[17]*pz + cc[22];
        s += e; sgx += e*gx; sgy += e*gy;
    }
    float inv_s = 1.0f/s;
    float mex = sgx*inv_s, mey = sgy*inv_s;
    float cxx=0.f, cxy=0.f, cyy=0.f;
    for (int d=0; d<ND; ++d) {
        float e  = __expf(lg[(size_t)d*NPIX] - mxl);
        float dz = 4.0f + (float)d;
        float pz = p0z + dz*cc[8];
        float px = (p0x + dz*cc[2]) * pz;
        float py = (p0y + dz*cc[5]) * pz;
        float gx = cc[12]*px + cc[13]*py + cc[14]*pz + cc[21];
        float gy = cc[15]*px + cc[16]*py + cc[17]*pz + cc[22];
        float dxv = gx - mex, dyv = gy - mey;
        cxx += e*dxv*dxv; cxy += e*dxv*dyv; cyy += e*dyv*dyv;
    }
    const float k9 = inv_s * (1.0f/9.0f);
    cxx *= k9; cxy *= k9; cyy *= k9;

    float lo = lg[(size_t)ND*NPIX];
    float op = 1.0f/(1.0f + __expf(-lo));
    bool mask = op > 0.05f;

    const float SC = 0.02f, SH = 50.0f, SW = 50.0f;
    float my = -SH*(mey*SC) + 50.0f;
    float mx = -SW*(mex*SC) + 50.0f;
    float a  = SH*SH*(cyy*SC*SC) + 0.3f;
    float b  = SH*SW*(cxy*SC*SC);
    float c  = SW*SW*(cxx*SC*SC) + 0.3f;
    float det = a*c - b*b;
    bool valid = mask && (det > 0.0f);
    float A, Bc, C, qm, ri, rj;
    if (valid) {
        float idet = 1.0f/det;
        A = c*idet; Bc = -b*idet; C = a*idet;
        qm = 2.0f*__logf(255.0f*op);       // alpha>=1/255 <=> q<=qm
        ri = sqrtf(qm*a); rj = sqrtf(qm*c);
    } else { A=Bc=C=0.f; qm=-1.0f; ri=-1e30f; rj=-1e30f; }
    float* gp = gauss + (size_t)gi*8;
    gp[0]=my; gp[1]=mx; gp[2]=A; gp[3]=Bc; gp[4]=C; gp[5]=qm; gp[6]=ri; gp[7]=rj;

    unsigned long long bal = __ballot(mask);
    if ((threadIdx.x & 63) == 0) atomicAdd(ng, (float)__popcll(bal));
}

// bin gaussians into per-tile 64-g-word bitmasks (stride NWORDP)
__global__ __launch_bounds__(256) void build_masks_kernel(const float* __restrict__ gauss,
        unsigned long long* __restrict__ masks) {
    const int g = blockIdx.x*256 + threadIdx.x;
    const float4 g0 = *(const float4*)(gauss + ((size_t)g << 3));
    const float4 g1 = *(const float4*)(gauss + ((size_t)g << 3) + 4);
    if (g1.y < 0.0f) return;
    const float my = g0.x, mx = g0.y, ri = g1.z, rj = g1.w;
    int ti0 = (int)floorf((my - ri) * 0.25f);
    int ti1 = (int)floorf((my + ri) * 0.25f);
    int tj0 = (int)floorf((mx - rj) * 0.25f);
    int tj1 = (int)floorf((mx + rj) * 0.25f);
    ti0 = max(ti0, 0); tj0 = max(tj0, 0);
    ti1 = min(ti1, NTILE-1); tj1 = min(tj1, NTILE-1);
    const int wi = g >> 6;
    const unsigned long long bit = 1ull << (g & 63);
    for (int ti = ti0; ti <= ti1; ++ti)
        for (int tj = tj0; tj <= tj1; ++tj)
            atomicOr(&masks[(size_t)(ti*NTILE + tj)*NWORDP + wi], bit);
}

__device__ inline float eval_alpha(const float4 g0, const float4 g1, float fi, float fj) {
    float dI = fi - g0.x, dJ = fj - g0.y;
    float q = dI*(g0.z*dI + 2.0f*g0.w*dJ) + g1.x*dJ*dJ;
    if (q < 0.0f || q > g1.y) return 0.0f;
    return fminf(0.99f, 0.003921568627f * __expf(0.5f*(g1.y - q)));
}

// per (tile, seg): S[tile][px][seg] = sum of log(1-alpha). Dense hit list,
// per-thread hit ownership (no divergence), shfl reduction once per block.
__global__ __launch_bounds__(256) void seg_sums_kernel(const float* __restrict__ gauss,
        const unsigned long long* __restrict__ masks, float* __restrict__ B) {
    __shared__ unsigned long long s_words[SEGW];
    __shared__ int s_off[SEGW+1];
    __shared__ unsigned short slist[SEGW*64];
    __shared__ float s_part[4][16];
    const int tile = blockIdx.x, seg = blockIdx.y;
    const int t = threadIdx.x, wave = t>>6, lane = t&63;
    const int i0 = (tile / NTILE) * 4, j0 = (tile % NTILE) * 4;
    if (t < SEGW) s_words[t] = masks[(size_t)tile*NWORDP + seg*SEGW + t];
    __syncthreads();
    if (t == 0) {
        int off = 0;
        for (int w2=0; w2<SEGW; ++w2) { s_off[w2] = off; off += __popcll(s_words[w2]); }
        s_off[SEGW] = off;
    }
    __syncthreads();
    if (t < SEGW) {
        unsigned long long m = s_words[t];
        int pos = s_off[t], base = t << 6;
        while (m) { int b = __builtin_ctzll(m); m &= m - 1; slist[pos++] = (unsigned short)(base + b); }
    }
    __syncthreads();
    const int cnt = s_off[SEGW];
    const int gseg = (seg*SEGW) << 6;
    float ls[16];
    #pragma unroll
    for (int p=0;p<16;p++) ls[p] = 0.f;
    for (int k=t; k<cnt; k+=256) {
        int g = gseg + slist[k];
        float4 g0 = *(const float4*)(gauss + ((size_t)g << 3));
        float4 g1 = *(const float4*)(gauss + ((size_t)g << 3) + 4);
        #pragma unroll
        for (int p=0;p<16;p++) {
            float a = eval_alpha(g0, g1, (float)(i0 + (p>>2)), (float)(j0 + (p&3)));
            if (a > 0.f) ls[p] += __logf(1.0f - a);
        }
    }
    #pragma unroll
    for (int p=0;p<16;p++) {
        #pragma unroll
        for (int off=32; off>=1; off>>=1) ls[p] += __shfl_down(ls[p], (unsigned)off, 64);
    }
    if (lane == 0) {
        #pragma unroll
        for (int p=0;p<16;p++) s_part[wave][p] = ls[p];
    }
    __syncthreads();
    if (t < 16)
        B[(size_t)(tile*16 + t)*NSEG + seg] = s_part[0][t]+s_part[1][t]+s_part[2][t]+s_part[3][t];
}

// per (tile, seg): dense ordered list, uniform branchless serial-T loop with
// 2-deep prefetch, ZERO syncthreads in the main loop. 16 px x 16 channel-groups.
__global__ __launch_bounds__(256) void composite_kernel(const float* __restrict__ gauss,
        const float* __restrict__ colors, const unsigned long long* __restrict__ masks,
        const float* __restrict__ B, float* __restrict__ out) {
    __shared__ unsigned long long s_words[SEGW];
    __shared__ int s_off[SEGW+1];
    __shared__ unsigned short slist[SEGW*64];
    __shared__ float s_base[16];
    const int tile = blockIdx.x, seg = blockIdx.y;
    const int t = threadIdx.x;
    const int i0 = (tile / NTILE) * 4, j0 = (tile % NTILE) * 4;
    if (t < SEGW) s_words[t] = masks[(size_t)tile*NWORDP + seg*SEGW + t];
    if (t < 16) {
        float b = 0.f;
        for (int s = 0; s < seg; ++s) b += B[(size_t)(tile*16 + t)*NSEG + s];
        s_base[t] = b;
    }
    __syncthreads();
    if (t == 0) {
        int off = 0;
        for (int w2=0; w2<SEGW; ++w2) { s_off[w2] = off; off += __popcll(s_words[w2]); }
        s_off[SEGW] = off;
    }
    __syncthreads();
    if (t < SEGW) {
        unsigned long long m = s_words[t];
        int pos = s_off[t], base = t << 6;
        while (m) { int b = __builtin_ctzll(m); m &= m - 1; slist[pos++] = (unsigned short)(base + b); }
    }
    __syncthreads();
    const int cnt = s_off[SEGW];
    if (cnt == 0) return;

    const int cs = t & 15, px = t >> 4;
    const float fi = (float)(i0 + (px >> 2)), fj = (float)(j0 + (px & 3));
    float T = __expf(s_base[px]);
    const int gseg = (seg*SEGW) << 6;
    float4 acc0 = make_float4(0.f,0.f,0.f,0.f);
    float4 acc1 = make_float4(0.f,0.f,0.f,0.f);

    // 2-deep prefetch pipeline
    float4 A0,A1,AC0,AC1, B0,B1,BC0,BC1;
    {
        int g = gseg + slist[0];
        const float* gp = gauss + ((size_t)g << 3);
        A0 = *(const float4*)gp; A1 = *(const float4*)(gp + 4);
        const float* cp = colors + ((size_t)g << 7) + (cs << 3);
        AC0 = *(const float4*)cp; AC1 = *(const float4*)(cp + 4);
    }
    if (cnt > 1) {
        int g = gseg + slist[1];
        const float* gp = gauss + ((size_t)g << 3);
        B0 = *(const float4*)gp; B1 = *(const float4*)(gp + 4);
        const float* cp = colors + ((size_t)g << 7) + (cs << 3);
        BC0 = *(const float4*)cp; BC1 = *(const float4*)(cp + 4);
    } else { B0=A0; B1=A1; BC0=AC0; BC1=AC1; }

    for (int k = 0; k < cnt; ++k) {
        float4 g0 = A0, g1 = A1, c0 = AC0, c1 = AC1;
        A0 = B0; A1 = B1; AC0 = BC0; AC1 = BC1;
        if (k + 2 < cnt) {
            int g = gseg + slist[k + 2];
            const float* gp = gauss + ((size_t)g << 3);
            B0 = *(const float4*)gp; B1 = *(const float4*)(gp + 4);
            const float* cp = colors + ((size_t)g << 7) + (cs << 3);
            BC0 = *(const float4*)cp; BC1 = *(const float4*)(cp + 4);
        }
        float dI = fi - g0.x, dJ = fj - g0.y;
        float q  = dI*(g0.z*dI + 2.0f*g0.w*dJ) + g1.x*dJ*dJ;
        float al = fminf(0.99f, 0.003921568627f * __expf(0.5f*(g1.y - q)));
        al = (q >= 0.0f && q <= g1.y) ? al : 0.0f;
        float wv = al * T; T -= wv;
        acc0.x = fmaf(wv, c0.x, acc0.x); acc0.y = fmaf(wv, c0.y, acc0.y);
        acc0.z = fmaf(wv, c0.z, acc0.z); acc0.w = fmaf(wv, c0.w, acc0.w);
        acc1.x = fmaf(wv, c1.x, acc1.x); acc1.y = fmaf(wv, c1.y, acc1.y);
        acc1.z = fmaf(wv, c1.z, acc1.z); acc1.w = fmaf(wv, c1.w, acc1.w);
    }

    const int pixg = (i0 + (px >> 2)) * BEVW + (j0 + (px & 3));
    float* op = out + (size_t)(cs << 3) * NPXB + pixg;
    atomicAdd(op + 0*NPXB, acc0.x); atomicAdd(op + 1*NPXB, acc0.y);
    atomicAdd(op + 2*NPXB, acc0.z); atomicAdd(op + 3*NPXB, acc0.w);
    atomicAdd(op + 4*NPXB, acc1.x); atomicAdd(op + 5*NPXB, acc1.y);
    atomicAdd(op + 6*NPXB, acc1.z); atomicAdd(op + 7*NPXB, acc1.w);
}

extern "C" void kernel_launch(void* const* d_in, const int* in_sizes, int n_in,
                              void* d_out, int out_size, void* d_ws, size_t ws_size,
                              hipStream_t stream) {
    const float* rot  = (const float*)d_in[0];
    const float* tr   = (const float*)d_in[1];
    const float* intr = (const float*)d_in[2];
    const float* prot = (const float*)d_in[3];
    const float* ptr_ = (const float*)d_in[4];
    const float* img  = (const float*)d_in[5];
    const float* c1w  = (const float*)d_in[6];  const float* c1b = (const float*)d_in[7];
    const float* b1g  = (const float*)d_in[8];  const float* b1b = (const float*)d_in[9];
    const float* b1m  = (const float*)d_in[10]; const float* b1v = (const float*)d_in[11];
    const float* c2w  = (const float*)d_in[12]; const float* c2b = (const float*)d_in[13];
    const float* b2g  = (const float*)d_in[14]; const float* b2b = (const float*)d_in[15];
    const float* b2m  = (const float*)d_in[16]; const float* b2v = (const float*)d_in[17];
    const float* c3w  = (const float*)d_in[18]; const float* c3b = (const float*)d_in[19];
    float* out = (float*)d_out;
    float* ws  = (float*)d_ws;
    float* CAM = ws + WS_CAM;
    float* RA  = ws + WS_A;    // IMGP -> X2P -> masks/Bsums
    float* RB  = ws + WS_RB;   // X1P -> colors
    float* X3B = ws + WS_X3;
    float* GS  = ws + WS_GS;
    unsigned long long* MASKS = (unsigned long long*)RA;
    float* Bsums = RA + A_BSUM;
    float* ngp = out + (size_t)NPXB*OUTC;

    cam_consts_kernel<<<1, 64, 0, stream>>>(rot, tr, intr, prot, ptr_, CAM);
    // zero both padded regions (borders must be 0 for conv windows)
    (void)hipMemsetAsync(RA, 0, (size_t)NCAM*FC*PPIX*sizeof(float), stream);
    (void)hipMemsetAsync(RB, 0, (size_t)NCAM*FC*PPIX*sizeof(float), stream);
    pad_input_kernel<<<NCAM*FC*NPIX/256, 256, 0, stream>>>(img, RA);          // img -> IMGP(A)
    conv3x3_q_kernel<<<dim3(NCAM,32,3), 256, 0, stream>>>(RA, RB, c1w, c1b, b1g, b1b, b1m, b1v); // A->B
    conv3x3_q_kernel<<<dim3(NCAM,32,3), 256, 0, stream>>>(RB, RA, c2w, c2b, b2g, b2b, b2m, b2v); // B->A
    conv1x1_kernel<<<dim3(NCAM,43,11), 256, 0, stream>>>(RA, X3B, RB, c3w, c3b);                 // A->X3B,colors(B)
    // region A dead -> masks + seg sums
    (void)hipMemsetAsync(MASKS, 0, (size_t)NTILE*NTILE*NWORDP*sizeof(unsigned long long), stream);
    (void)hipMemsetAsync(ngp, 0, sizeof(float), stream);
    (void)hipMemsetAsync(out, 0, (size_t)NPXB*OUTC*sizeof(float), stream);
    moments_kernel<<<GTOT/256, 256, 0, stream>>>(X3B, CAM, GS, ngp);
    build_masks_kernel<<<GTOT/256, 256, 0, stream>>>(GS, MASKS);
    seg_sums_kernel<<<dim3(NTILE*NTILE, NSEG), 256, 0, stream>>>(GS, MASKS, Bsums);
    composite_kernel<<<dim3(NTILE*NTILE, NSEG), 256, 0, stream>>>(GS, RB, MASKS, Bsums, out);
}

// Round 7
// 593.995 us; speedup vs baseline: 1.3844x; 1.3324x over previous
//
#include <hip/hip_runtime.h>

#define NCAM 6
#define FC   128
#define FH_  32
#define FW_  88
#define NPIX (FH_*FW_)        // 2816
#define PH   34
#define PW   92               // padded width (mult of 4 -> float4-aligned rows)
#define PPIX (PH*PW)          // 3128
#define ND   41
#define X3D  42               // 41 depth + 1 opacity planes
#define OUTC 128
#define GTOT (NCAM*NPIX)      // 16896
#define BEVH 100
#define BEVW 100
#define NPXB (BEVH*BEVW)      // 10000
#define NTILE 25              // 25x25 tiles of 4x4 px
#define NWORD 264             // 16896/64 mask words per tile
#define WCAP  70000           // worklist capacity (chunks)
#define CSIZE 64              // hits per chunk

// ---- ws layout (float offsets). Total ~6.84M floats = 27.4 MB ----
#define SZA     (NCAM*FC*PPIX)           // 2402304
#define WS_CAM  0
#define WS_A    256                      // IMGP -> X2P -> hit lists (ushort)
#define WS_RB   (WS_A  + SZA)            // X1P -> colors
#define WS_X3   (WS_RB + SZA)            // depth+opacity planes -> masks+aux
#define WS_GS   (WS_X3 + NCAM*X3D*NPIX)  // gauss params 16896*8
#define WS_WL   (WS_GS + GTOT*8)         // worklist ints
#define WS_BASE (WS_WL + WCAP)           // per-chunk per-px bases WCAP*16

__device__ inline void inv3x3(const float* m, float* o) {
    float a=m[0],b=m[1],c=m[2],d=m[3],e=m[4],f=m[5],g=m[6],h=m[7],i=m[8];
    float A=e*i-f*h, B=c*h-b*i, C=b*f-c*e;
    float Dd=f*g-d*i, E=a*i-c*g, F=c*d-a*f;
    float Gg=d*h-e*g, H=b*g-a*h, I=a*e-b*d;
    float r = 1.0f/(a*A + b*Dd + c*Gg);
    o[0]=A*r; o[1]=B*r; o[2]=C*r; o[3]=Dd*r; o[4]=E*r; o[5]=F*r;
    o[6]=Gg*r; o[7]=H*r; o[8]=I*r;
}

__global__ void cam_consts_kernel(const float* __restrict__ rot, const float* __restrict__ tr,
                                  const float* __restrict__ intr, const float* __restrict__ prot,
                                  const float* __restrict__ ptr_, float* __restrict__ cam) {
    int n = threadIdx.x;
    if (n >= NCAM) return;
    float M1[9], Ki[9];
    inv3x3(prot + n*9, M1);
    inv3x3(intr + n*9, Ki);
    const float* R = rot + n*9;
    float* c = cam + n*24;
    for (int i=0;i<9;i++) c[i] = M1[i];
    for (int i=0;i<3;i++) c[9+i] = ptr_[n*3+i];
    for (int i=0;i<3;i++)
        for (int j=0;j<3;j++)
            c[12+i*3+j] = R[i*3+0]*Ki[0+j] + R[i*3+1]*Ki[3+j] + R[i*3+2]*Ki[6+j];
    for (int i=0;i<3;i++) c[21+i] = tr[n*3+i];
}

__global__ __launch_bounds__(256) void pad_input_kernel(const float* __restrict__ src,
                                                        float* __restrict__ dst) {
    int idx = blockIdx.x*256 + threadIdx.x;
    int plane = idx / NPIX, px = idx - plane*NPIX;
    int y = px / FW_, x = px - y*FW_;
    dst[(size_t)plane*PPIX + (y+1)*PW + (x+1)] = src[idx];
}

// 3x3 conv + folded BN + ReLU, 4 px/thread, padded in/out, float4 window loads.
__global__ __launch_bounds__(256) void conv3x3_q_kernel(
        const float* __restrict__ in, float* __restrict__ out, const float* __restrict__ w,
        const float* __restrict__ cb, const float* __restrict__ bg, const float* __restrict__ bb,
        const float* __restrict__ bm, const float* __restrict__ bv) {
    const int n   = blockIdx.x;
    const int co0 = blockIdx.y * 4;
    const int qid = blockIdx.z * 256 + threadIdx.x;
    if (qid >= 704) return;
    const int y = qid / 22, x0 = (qid - y*22) * 4;
    float scale[4], shift[4];
    #pragma unroll
    for (int c=0;c<4;c++) {
        float s = bg[co0+c] * rsqrtf(bv[co0+c] + 1e-3f);
        scale[c] = s;
        shift[c] = (cb[co0+c] - bm[co0+c]) * s + bb[co0+c];
    }
    float acc[4][4] = {};
    const float* ip = in + (size_t)n*FC*PPIX + y*PW + x0;
    const float* wb = w + (size_t)co0*FC*9;
    for (int ci=0; ci<FC; ++ci) {
        float v[3][6];
        #pragma unroll
        for (int r=0;r<3;r++) {
            float4 q4 = *(const float4*)(ip + r*PW);
            float2 q2 = *(const float2*)(ip + r*PW + 4);
            v[r][0]=q4.x; v[r][1]=q4.y; v[r][2]=q4.z; v[r][3]=q4.w; v[r][4]=q2.x; v[r][5]=q2.y;
        }
        #pragma unroll
        for (int c=0;c<4;c++) {
            const float* wr = wb + (size_t)c*FC*9 + ci*9;
            float w00=wr[0],w01=wr[1],w02=wr[2],w10=wr[3],w11=wr[4],
                  w12=wr[5],w20=wr[6],w21=wr[7],w22=wr[8];
            #pragma unroll
            for (int p=0;p<4;p++) {
                float a = acc[c][p];
                a = fmaf(w00, v[0][p], a); a = fmaf(w01, v[0][p+1], a); a = fmaf(w02, v[0][p+2], a);
                a = fmaf(w10, v[1][p], a); a = fmaf(w11, v[1][p+1], a); a = fmaf(w12, v[1][p+2], a);
                a = fmaf(w20, v[2][p], a); a = fmaf(w21, v[2][p+1], a); a = fmaf(w22, v[2][p+2], a);
                acc[c][p] = a;
            }
        }
        ip += PPIX;
    }
    #pragma unroll
    for (int c=0;c<4;c++) {
        float* op = out + ((size_t)n*FC + co0 + c)*PPIX + (y+1)*PW + (x0+1);
        #pragma unroll
        for (int p=0;p<4;p++)
            op[p] = fmaxf(fmaf(acc[c][p], scale[c], shift[c]), 0.0f);
    }
}

__global__ __launch_bounds__(256) void conv1x1_kernel(const float* __restrict__ in,
        float* __restrict__ x3d, float* __restrict__ colors,
        const float* __restrict__ w, const float* __restrict__ b) {
    const int n  = blockIdx.x;
    const int g  = blockIdx.y;                   // 0..42
    const int t  = threadIdx.x;
    const int px = blockIdx.z * 256 + t;
    const int y  = px / FW_, x = px - y*FW_;
    const int pp = (y+1)*PW + (x+1);
    const bool iscolor = (g >= 11);
    const int co0 = iscolor ? (42 + 4*(g-11)) : g*4;
    const int nc  = (g == 10) ? 2 : 4;
    float acc[4];
    #pragma unroll
    for (int c=0;c<4;c++) acc[c] = (c < nc) ? b[co0+c] : 0.0f;
    const float* ip = in + (size_t)n*FC*PPIX + pp;
    for (int ci=0; ci<FC; ++ci) {
        float v = ip[(size_t)ci*PPIX];
        #pragma unroll
        for (int c=0;c<4;c++)
            if (c < nc) acc[c] = fmaf(w[(size_t)(co0+c)*FC + ci], v, acc[c]);
    }
    if (iscolor) {
        *(float4*)(colors + (((size_t)(n*NPIX + px)) << 7) + (co0 - 42)) =
            make_float4(acc[0], acc[1], acc[2], acc[3]);
    } else {
        #pragma unroll
        for (int c=0;c<4;c++)
            if (c < nc) x3d[((size_t)n*X3D + co0 + c)*NPIX + px] = acc[c];
    }
}

// per-gaussian: softmax moments, splat params {my,mx,A,2B,C,qm,ri,rj}
__global__ __launch_bounds__(256) void moments_kernel(const float* __restrict__ x3,
        const float* __restrict__ cam, float* __restrict__ gauss, float* __restrict__ ng) {
    int gi = blockIdx.x*256 + threadIdx.x;
    int n  = gi / NPIX;
    int p  = gi - n*NPIX;
    int h  = p / FW_, xp = p - h*FW_;
    const float* cc = cam + n*24;
    float u = xp * (703.0f/87.0f);
    float v = h  * (255.0f/31.0f);
    float fx = u - cc[9], fy = v - cc[10], fz = -cc[11];
    float p0x = cc[0]*fx + cc[1]*fy + cc[2]*fz;
    float p0y = cc[3]*fx + cc[4]*fy + cc[5]*fz;
    float p0z = cc[6]*fx + cc[7]*fy + cc[8]*fz;
    const float* lg = x3 + (size_t)n*X3D*NPIX + p;

    float mxl = -1e30f;
    for (int d=0; d<ND; ++d) mxl = fmaxf(mxl, lg[(size_t)d*NPIX]);
    float s=0.f, sgx=0.f, sgy=0.f;
    for (int d=0; d<ND; ++d) {
        float e  = __expf(lg[(size_t)d*NPIX] - mxl);
        float dz = 4.0f + (float)d;
        float pz = p0z + dz*cc[8];
        float px = (p0x + dz*cc[2]) * pz;
        float py = (p0y + dz*cc[5]) * pz;
        float gx = cc[12]*px + cc[13]*py + cc[14]*pz + cc[21];
        float gy = cc[15]*px + cc[16]*py + cc[17]*pz + cc[22];
        s += e; sgx += e*gx; sgy += e*gy;
    }
    float inv_s = 1.0f/s;
    float mex = sgx*inv_s, mey = sgy*inv_s;
    float cxx=0.f, cxy=0.f, cyy=0.f;
    for (int d=0; d<ND; ++d) {
        float e  = __expf(lg[(size_t)d*NPIX] - mxl);
        float dz = 4.0f + (float)d;
        float pz = p0z + dz*cc[8];
        float px = (p0x + dz*cc[2]) * pz;
        float py = (p0y + dz*cc[5]) * pz;
        float gx = cc[12]*px + cc[13]*py + cc[14]*pz + cc[21];
        float gy = cc[15]*px + cc[16]*py + cc[17]*pz + cc[22];
        float dxv = gx - mex, dyv = gy - mey;
        cxx += e*dxv*dxv; cxy += e*dxv*dyv; cyy += e*dyv*dyv;
    }
    const float k9 = inv_s * (1.0f/9.0f);
    cxx *= k9; cxy *= k9; cyy *= k9;

    float lo = lg[(size_t)ND*NPIX];
    float op = 1.0f/(1.0f + __expf(-lo));
    bool mask = op > 0.05f;

    const float SC = 0.02f, SH = 50.0f, SW = 50.0f;
    float my = -SH*(mey*SC) + 50.0f;
    float mx = -SW*(mex*SC) + 50.0f;
    float a  = SH*SH*(cyy*SC*SC) + 0.3f;
    float b  = SH*SW*(cxy*SC*SC);
    float c  = SW*SW*(cxx*SC*SC) + 0.3f;
    float det = a*c - b*b;
    bool valid = mask && (det > 0.0f);
    float A, B2, C, qm, ri, rj;
    if (valid) {
        float idet = 1.0f/det;
        A = c*idet; B2 = -2.0f*b*idet; C = a*idet;
        qm = 2.0f*__logf(255.0f*op);
        ri = sqrtf(qm*a); rj = sqrtf(qm*c);
    } else { A=B2=C=0.f; qm=-1.0f; ri=-1e30f; rj=-1e30f; }
    float* gp = gauss + (size_t)gi*8;
    gp[0]=my; gp[1]=mx; gp[2]=A; gp[3]=B2; gp[4]=C; gp[5]=qm; gp[6]=ri; gp[7]=rj;

    unsigned long long bal = __ballot(mask);
    if ((threadIdx.x & 63) == 0) atomicAdd(ng, (float)__popcll(bal));
}

// exact per-row ellipse interval culling -> tile bitmasks
__global__ __launch_bounds__(256) void build_masks_kernel(const float* __restrict__ gauss,
        unsigned long long* __restrict__ masks) {
    const int g = blockIdx.x*256 + threadIdx.x;
    const float4 g0 = *(const float4*)(gauss + ((size_t)g << 3));      // my,mx,A,2B
    const float4 g1 = *(const float4*)(gauss + ((size_t)g << 3) + 4);  // C,qm,ri,rj
    if (g1.y < 0.0f) return;
    const float my = g0.x, mx = g0.y, A = g0.z, B = 0.5f*g0.w, C = g1.x, qm = g1.y, ri = g1.z;
    const float invC = 1.0f / C;
    const float k2 = C*A - B*B;          // > 0
    int ti0 = max(0, (int)floorf((my - ri) * 0.25f));
    int ti1 = min(NTILE-1, (int)floorf((my + ri) * 0.25f));
    const int wi = g >> 6;
    const unsigned long long bit = 1ull << (g & 63);
    for (int ti = ti0; ti <= ti1; ++ti) {
        float jmn = 1e30f, jmx = -1e30f;
        #pragma unroll
        for (int r = 0; r < 4; ++r) {
            int i = 4*ti + r;
            if (i < 0 || i > 99) continue;
            float di = (float)i - my;
            float disc = C*qm - k2*di*di;
            if (disc < 0.0f) continue;
            float sd = sqrtf(disc);
            float jc = -B*di;
            jmn = fminf(jmn, (jc - sd)*invC + mx);
            jmx = fmaxf(jmx, (jc + sd)*invC + mx);
        }
        if (jmx < jmn) continue;
        int jl = max(0, (int)ceilf(jmn));
        int jh = min(99, (int)floorf(jmx));
        if (jl > jh) continue;
        for (int tj = (jl >> 2); tj <= (jh >> 2); ++tj)
            atomicOr(&masks[(size_t)(ti*NTILE + tj)*NWORD + wi], bit);
    }
}

// per-tile hit count
__global__ __launch_bounds__(256) void cnt_kernel(const unsigned long long* __restrict__ masks,
                                                  int* __restrict__ cnt) {
    __shared__ int sc;
    const int tile = blockIdx.x, t = threadIdx.x;
    if (t == 0) sc = 0;
    __syncthreads();
    if (t < NWORD) atomicAdd(&sc, __popcll(masks[(size_t)tile*NWORD + t]));
    __syncthreads();
    if (t == 0) cnt[tile] = sc;
}

// serial scans over 625 tiles: list offsets, chunk offsets, total chunks
__global__ void scan_kernel(const int* __restrict__ cnt, int* __restrict__ off,
                            int* __restrict__ choff, int* __restrict__ nwork) {
    if (threadIdx.x != 0) return;
    int run = 0;
    for (int i = 0; i < NTILE*NTILE; ++i) { off[i] = run; run += cnt[i]; }
    off[NTILE*NTILE] = run;
    int run2 = 0;
    for (int i = 0; i < NTILE*NTILE; ++i) { choff[i] = run2; run2 += (cnt[i] + CSIZE-1)/CSIZE; }
    choff[NTILE*NTILE] = run2;
    nwork[0] = (run2 > WCAP) ? WCAP : run2;
}

// expand bitmasks -> dense ordered hit lists + chunk worklist
__global__ __launch_bounds__(256) void fill_kernel(const unsigned long long* __restrict__ masks,
        const int* __restrict__ cnt, const int* __restrict__ off, const int* __restrict__ choff,
        unsigned short* __restrict__ list, int* __restrict__ wl) {
    __shared__ unsigned long long sw[NWORD];
    __shared__ int wpre[NWORD];
    const int tile = blockIdx.x, t = threadIdx.x;
    if (t < NWORD) sw[t] = masks[(size_t)tile*NWORD + t];
    __syncthreads();
    if (t == 0) {
        int run = 0;
        for (int w2 = 0; w2 < NWORD; ++w2) { wpre[w2] = run; run += __popcll(sw[w2]); }
    }
    __syncthreads();
    if (t < NWORD) {
        unsigned long long m = sw[t];
        int pos = off[tile] + wpre[t], base = t << 6;
        while (m) { int b = __builtin_ctzll(m); m &= m - 1; list[pos++] = (unsigned short)(base + b); }
    }
    int nch = (cnt[tile] + CSIZE-1)/CSIZE;
    int c0 = choff[tile];
    if (t < nch && c0 + t < WCAP) wl[c0 + t] = (tile << 9) | t;
}

__device__ inline float eval_alpha(const float4 g0, const float4 g1, float fi, float fj) {
    float dI = fi - g0.x, dJ = fj - g0.y;
    float q = dI*(g0.z*dI + g0.w*dJ) + g1.x*dJ*dJ;     // g0.w = 2B
    if (q < 0.0f || q > g1.y) return 0.0f;
    return fminf(0.99f, 0.003921568627f * __expf(0.5f*(g1.y - q)));
}

// per chunk: per-px sums of log(1-alpha) -> BASE[e][px] (pre-prefix)
__global__ __launch_bounds__(256) void chunk_sums_kernel(const float* __restrict__ gauss,
        const unsigned short* __restrict__ list, const int* __restrict__ cnt,
        const int* __restrict__ off, const int* __restrict__ wl, const int* __restrict__ nwork,
        float* __restrict__ base) {
    const int nw = nwork[0];
    const int t = threadIdx.x;
    const int px = t & 15, kg = t >> 4;
    __shared__ unsigned short slist[CSIZE];
    __shared__ float red[16][17];
    for (int e = blockIdx.x; e < nw; e += gridDim.x) {
        int v = wl[e], tile = v >> 9, c = v & 511;
        int hbase = off[tile] + (c << 6);
        int nh = min(CSIZE, cnt[tile] - (c << 6));
        if (t < nh) slist[t] = list[hbase + t];
        __syncthreads();
        const int i0 = (tile / NTILE) * 4, j0 = (tile % NTILE) * 4;
        const float fi = (float)(i0 + (px >> 2)), fj = (float)(j0 + (px & 3));
        float s = 0.0f;
        for (int k = kg; k < nh; k += 16) {
            int g = slist[k];
            float4 g0 = *(const float4*)(gauss + ((size_t)g << 3));
            float4 g1 = *(const float4*)(gauss + ((size_t)g << 3) + 4);
            float a = eval_alpha(g0, g1, fi, fj);
            if (a > 0.0f) s += __logf(1.0f - a);
        }
        red[kg][px] = s;
        __syncthreads();
        if (t < 16) {
            float acc = 0.0f;
            #pragma unroll
            for (int k2 = 0; k2 < 16; ++k2) acc += red[k2][t];
            base[(size_t)e*16 + t] = acc;
        }
        __syncthreads();
    }
}

// per tile: exclusive prefix of chunk sums (in place) -> chunk-start log-T bases
__global__ __launch_bounds__(256) void chunk_prefix_kernel(const int* __restrict__ choff,
                                                           float* __restrict__ base) {
    __shared__ float part[16][17];
    const int tile = blockIdx.x, t = threadIdx.x;
    const int c0 = choff[tile], nch = choff[tile+1] - c0;
    if (nch == 0) return;
    const int px = t & 15, cg = t >> 4;
    const int L16 = (nch + 15) >> 4;
    const int a0 = cg*L16, a1 = min(nch, a0 + L16);
    float s = 0.0f;
    for (int c = a0; c < a1; ++c) s += base[(size_t)(c0 + c)*16 + px];
    part[cg][px] = s;
    __syncthreads();
    if (t < 16) {
        float run = 0.0f;
        #pragma unroll
        for (int k = 0; k < 16; ++k) { float tmp = part[k][t]; part[k][t] = run; run += tmp; }
    }
    __syncthreads();
    float run = part[cg][px];
    for (int c = a0; c < a1; ++c) {
        size_t idx = (size_t)(c0 + c)*16 + px;
        float tmp = base[idx];
        base[idx] = run;
        run += tmp;
    }
}

// balanced composite: grid-stride over 64-hit chunks, serial T per px, (px,cs) threads
__global__ __launch_bounds__(256) void composite_kernel(const float* __restrict__ gauss,
        const float* __restrict__ colors, const unsigned short* __restrict__ list,
        const int* __restrict__ cnt, const int* __restrict__ off, const int* __restrict__ wl,
        const int* __restrict__ nwork, const float* __restrict__ base, float* __restrict__ out) {
    const int nw = nwork[0];
    const int t = threadIdx.x;
    const int px = t >> 4, cs = t & 15;
    __shared__ unsigned short slist[CSIZE];
    for (int e = blockIdx.x; e < nw; e += gridDim.x) {
        int v = wl[e], tile = v >> 9, c = v & 511;
        int hbase = off[tile] + (c << 6);
        int nh = min(CSIZE, cnt[tile] - (c << 6));
        if (t < nh) slist[t] = list[hbase + t];
        __syncthreads();
        const int i0 = (tile / NTILE) * 4, j0 = (tile % NTILE) * 4;
        const float fi = (float)(i0 + (px >> 2)), fj = (float)(j0 + (px & 3));
        float T = __expf(base[(size_t)e*16 + px]);
        float4 acc0 = make_float4(0.f,0.f,0.f,0.f);
        float4 acc1 = make_float4(0.f,0.f,0.f,0.f);
        for (int k = 0; k < nh; ++k) {
            int g = slist[k];
            const float* gp = gauss + ((size_t)g << 3);
            float4 g0 = *(const float4*)gp;
            float4 g1 = *(const float4*)(gp + 4);
            float dI = fi - g0.x, dJ = fj - g0.y;
            float q  = dI*(g0.z*dI + g0.w*dJ) + g1.x*dJ*dJ;
            float al = fminf(0.99f, 0.003921568627f * __expf(0.5f*(g1.y - q)));
            al = (q >= 0.0f && q <= g1.y) ? al : 0.0f;
            float wv = al * T; T -= wv;
            if (__any(wv > 0.0f)) {
                const float* cp = colors + ((size_t)g << 7) + (cs << 3);
                float4 c0 = *(const float4*)cp;
                float4 c1 = *(const float4*)(cp + 4);
                acc0.x = fmaf(wv, c0.x, acc0.x); acc0.y = fmaf(wv, c0.y, acc0.y);
                acc0.z = fmaf(wv, c0.z, acc0.z); acc0.w = fmaf(wv, c0.w, acc0.w);
                acc1.x = fmaf(wv, c1.x, acc1.x); acc1.y = fmaf(wv, c1.y, acc1.y);
                acc1.z = fmaf(wv, c1.z, acc1.z); acc1.w = fmaf(wv, c1.w, acc1.w);
            }
        }
        const int pixg = (i0 + (px >> 2)) * BEVW + (j0 + (px & 3));
        float* op = out + (size_t)(cs << 3) * NPXB + pixg;
        atomicAdd(op + 0*NPXB, acc0.x); atomicAdd(op + 1*NPXB, acc0.y);
        atomicAdd(op + 2*NPXB, acc0.z); atomicAdd(op + 3*NPXB, acc0.w);
        atomicAdd(op + 4*NPXB, acc1.x); atomicAdd(op + 5*NPXB, acc1.y);
        atomicAdd(op + 6*NPXB, acc1.z); atomicAdd(op + 7*NPXB, acc1.w);
        __syncthreads();
    }
}

extern "C" void kernel_launch(void* const* d_in, const int* in_sizes, int n_in,
                              void* d_out, int out_size, void* d_ws, size_t ws_size,
                              hipStream_t stream) {
    const float* rot  = (const float*)d_in[0];
    const float* tr   = (const float*)d_in[1];
    const float* intr = (const float*)d_in[2];
    const float* prot = (const float*)d_in[3];
    const float* ptr_ = (const float*)d_in[4];
    const float* img  = (const float*)d_in[5];
    const float* c1w  = (const float*)d_in[6];  const float* c1b = (const float*)d_in[7];
    const float* b1g  = (const float*)d_in[8];  const float* b1b = (const float*)d_in[9];
    const float* b1m  = (const float*)d_in[10]; const float* b1v = (const float*)d_in[11];
    const float* c2w  = (const float*)d_in[12]; const float* c2b = (const float*)d_in[13];
    const float* b2g  = (const float*)d_in[14]; const float* b2b = (const float*)d_in[15];
    const float* b2m  = (const float*)d_in[16]; const float* b2v = (const float*)d_in[17];
    const float* c3w  = (const float*)d_in[18]; const float* c3b = (const float*)d_in[19];
    float* out = (float*)d_out;
    float* ws  = (float*)d_ws;
    float* CAM = ws + WS_CAM;
    float* RA  = ws + WS_A;    // IMGP -> X2P -> lists
    float* RB  = ws + WS_RB;   // X1P -> colors
    float* X3B = ws + WS_X3;   // planes -> masks+aux
    float* GS  = ws + WS_GS;
    int*   WL  = (int*)(ws + WS_WL);
    float* BASE = ws + WS_BASE;
    unsigned long long* MASKS = (unsigned long long*)X3B;
    int* AUXI = (int*)(ws + WS_X3 + 330000);
    int* CNT = AUXI;           // 625
    int* OFF = AUXI + 640;     // 626
    int* CHOFF = AUXI + 1280;  // 626
    int* NWORK = AUXI + 1920;  // 1
    unsigned short* LIST = (unsigned short*)RA;
    float* COL = RB;
    float* ngp = out + (size_t)NPXB*OUTC;

    cam_consts_kernel<<<1, 64, 0, stream>>>(rot, tr, intr, prot, ptr_, CAM);
    (void)hipMemsetAsync(RA, 0, (size_t)SZA*sizeof(float), stream);
    (void)hipMemsetAsync(RB, 0, (size_t)SZA*sizeof(float), stream);
    pad_input_kernel<<<NCAM*FC*NPIX/256, 256, 0, stream>>>(img, RA);
    conv3x3_q_kernel<<<dim3(NCAM,32,3), 256, 0, stream>>>(RA, RB, c1w, c1b, b1g, b1b, b1m, b1v);
    conv3x3_q_kernel<<<dim3(NCAM,32,3), 256, 0, stream>>>(RB, RA, c2w, c2b, b2g, b2b, b2m, b2v);
    conv1x1_kernel<<<dim3(NCAM,43,11), 256, 0, stream>>>(RA, X3B, COL, c3w, c3b);
    (void)hipMemsetAsync(ngp, 0, sizeof(float), stream);
    (void)hipMemsetAsync(out, 0, (size_t)NPXB*OUTC*sizeof(float), stream);
    moments_kernel<<<GTOT/256, 256, 0, stream>>>(X3B, CAM, GS, ngp);
    // X3 planes dead -> masks + aux live there
    (void)hipMemsetAsync(MASKS, 0, (size_t)NTILE*NTILE*NWORD*sizeof(unsigned long long), stream);
    build_masks_kernel<<<GTOT/256, 256, 0, stream>>>(GS, MASKS);
    cnt_kernel<<<NTILE*NTILE, 256, 0, stream>>>(MASKS, CNT);
    scan_kernel<<<1, 64, 0, stream>>>(CNT, OFF, CHOFF, NWORK);
    fill_kernel<<<NTILE*NTILE, 256, 0, stream>>>(MASKS, CNT, OFF, CHOFF, LIST, WL);
    chunk_sums_kernel<<<8192, 256, 0, stream>>>(GS, LIST, CNT, OFF, WL, NWORK, BASE);
    chunk_prefix_kernel<<<NTILE*NTILE, 256, 0, stream>>>(CHOFF, BASE);
    composite_kernel<<<8192, 256, 0, stream>>>(GS, COL, LIST, CNT, OFF, WL, NWORK, BASE, out);
}